// Round 2
// baseline (135.036 us; speedup 1.0000x reference)
//
#include <hip/hip_runtime.h>

// Joint bilateral filter, 5x5, SAME zero padding.
// template: (1,3,1080,1920) fp32 planar; vector: (1,2,1080,1920) fp32 planar.
// out: (1,2,1080,1920) — reference dtype is fp16, but harness stores/reads
// non-bf16 outputs as FLOAT32 (decode: np.float32). Write f32.

#define IMG_H 1080
#define IMG_W 1920
#define TS_X 64      // tile width  (pixels)
#define TS_Y 16      // tile height (pixels)
#define HALO_H 20    // TS_Y + 4
#define HALO_W 72    // TS_X + 8 (need 68; 72 keeps float4 alignment)

__global__ __launch_bounds__(256)
void jbf_kernel(const float* __restrict__ tpl,
                const float* __restrict__ vec,
                float* __restrict__ out) {
    constexpr float KVAL  = -0.125f;  // -1/(2*sigma_spatial^2)
    constexpr float SIDIV = 50.0f;    // 1/(2*sigma_intensity^2)

    __shared__ __align__(16) float smem[5][HALO_H][HALO_W];

    const int tid = threadIdx.x;
    const int x0  = blockIdx.x * TS_X;
    const int y0  = blockIdx.y * TS_Y;

    // ---- stage haloed tile (zero-padded) ----
#pragma unroll
    for (int c = 0; c < 5; ++c) {
        const float* __restrict__ src =
            (c < 3) ? (tpl + c * (IMG_H * IMG_W)) : (vec + (c - 3) * (IMG_H * IMG_W));
        for (int i = tid; i < HALO_H * HALO_W; i += 256) {
            const int r   = i / HALO_W;
            const int col = i - r * HALO_W;
            const int gy  = y0 + r - 2;
            const int gx  = x0 + col - 2;
            float v = 0.0f;
            if (gy >= 0 && gy < IMG_H && gx >= 0 && gx < IMG_W)
                v = src[gy * IMG_W + gx];
            smem[c][r][col] = v;
        }
    }
    __syncthreads();

    const int tx = tid & 15;   // 16 threads across
    const int ty = tid >> 4;   // 16 rows
    const int lx = tx * 4;     // first of 4 pixels this thread owns (halo col base)

    float num0[4] = {0.f, 0.f, 0.f, 0.f};
    float num1[4] = {0.f, 0.f, 0.f, 0.f};
    float den [4] = {0.f, 0.f, 0.f, 0.f};

    float c0[4], c1[4], c2[4];
#pragma unroll
    for (int px = 0; px < 4; ++px) {
        c0[px] = smem[0][ty + 2][lx + 2 + px];
        c1[px] = smem[1][ty + 2][lx + 2 + px];
        c2[px] = smem[2][ty + 2][lx + 2 + px];
    }

#pragma unroll
    for (int dy = 0; dy < 5; ++dy) {
        const int row = ty + dy;
        float4 a0 = *(const float4*)&smem[0][row][lx];
        float4 b0 = *(const float4*)&smem[0][row][lx + 4];
        float4 a1 = *(const float4*)&smem[1][row][lx];
        float4 b1 = *(const float4*)&smem[1][row][lx + 4];
        float4 a2 = *(const float4*)&smem[2][row][lx];
        float4 b2 = *(const float4*)&smem[2][row][lx + 4];
        float4 av0 = *(const float4*)&smem[3][row][lx];
        float4 bv0 = *(const float4*)&smem[3][row][lx + 4];
        float4 av1 = *(const float4*)&smem[4][row][lx];
        float4 bv1 = *(const float4*)&smem[4][row][lx + 4];

        const float w0[8]  = {a0.x, a0.y, a0.z, a0.w, b0.x, b0.y, b0.z, b0.w};
        const float w1[8]  = {a1.x, a1.y, a1.z, a1.w, b1.x, b1.y, b1.z, b1.w};
        const float w2[8]  = {a2.x, a2.y, a2.z, a2.w, b2.x, b2.y, b2.z, b2.w};
        const float wv0[8] = {av0.x, av0.y, av0.z, av0.w, bv0.x, bv0.y, bv0.z, bv0.w};
        const float wv1[8] = {av1.x, av1.y, av1.z, av1.w, bv1.x, bv1.y, bv1.z, bv1.w};

#pragma unroll
        for (int dx = 0; dx < 5; ++dx) {
#pragma unroll
            for (int px = 0; px < 4; ++px) {
                const int k = dx + px;
                const float d0 = c0[px] - w0[k];
                const float d1 = c1[px] - w1[k];
                const float d2 = c2[px] - w2[k];
                const float id = d0 * d0 + d1 * d1 + d2 * d2;
                const float t  = fabsf(KVAL - id * SIDIV);
                float coeff = 1.0f - t;
                coeff = fminf(fmaxf(coeff, 0.0f), 1.0f);
                num0[px] += wv0[k] * coeff;
                num1[px] += wv1[k] * coeff;
                den [px] += coeff;
            }
        }
    }

    const int gy = y0 + ty;
    if (gy < IMG_H) {
        const int gx = x0 + lx;
        float4 o0, o1;
        float r0 = __builtin_amdgcn_rcpf(den[0]);
        float r1 = __builtin_amdgcn_rcpf(den[1]);
        float r2 = __builtin_amdgcn_rcpf(den[2]);
        float r3 = __builtin_amdgcn_rcpf(den[3]);
        o0.x = num0[0] * r0; o0.y = num0[1] * r1; o0.z = num0[2] * r2; o0.w = num0[3] * r3;
        o1.x = num1[0] * r0; o1.y = num1[1] * r1; o1.z = num1[2] * r2; o1.w = num1[3] * r3;
        *(float4*)(out + (size_t)0 * IMG_H * IMG_W + gy * IMG_W + gx) = o0;
        *(float4*)(out + (size_t)1 * IMG_H * IMG_W + gy * IMG_W + gx) = o1;
    }
}

extern "C" void kernel_launch(void* const* d_in, const int* in_sizes, int n_in,
                              void* d_out, int out_size, void* d_ws, size_t ws_size,
                              hipStream_t stream) {
    const float* tpl = (const float*)d_in[0];
    const float* vec = (const float*)d_in[1];
    float* out = (float*)d_out;

    dim3 grid(IMG_W / TS_X, (IMG_H + TS_Y - 1) / TS_Y);  // 30 x 68
    jbf_kernel<<<grid, 256, 0, stream>>>(tpl, vec, out);
}

// Round 3
// 109.178 us; speedup vs baseline: 1.2368x; 1.2368x over previous
//
#include <hip/hip_runtime.h>

// Joint bilateral filter 5x5, SAME zero padding.
// template: (1,3,1080,1920) f32 planar; vector: (1,2,1080,1920) f32 planar.
// out: (1,2,1080,1920) f32 (harness reads non-bf16 outputs as np.float32).
//
// Round 3: latency-bound fix. Interior blocks stage the 20x72 halo tile as
// 10 float4 (align-4) global loads per thread, two-phase (loads then LDS
// stores) to break the per-iteration load->store vmcnt(0) chain that
// serialized round 2's staging (VALUBusy was 28%, all pipes idle).

#define IMG_H 1080
#define IMG_W 1920
#define IMG_HW (IMG_H * IMG_W)
#define TS_X 64      // tile width  (pixels)
#define TS_Y 16      // tile height (pixels)
#define HALO_H 20    // TS_Y + 4
#define HALO_W 72    // TS_X + 8
#define NCH 5
#define F4_PER_ROW 18            // 72/4
#define F4_PER_CH  (F4_PER_ROW * HALO_H)   // 360

typedef float f4u __attribute__((ext_vector_type(4), aligned(4)));

__global__ __launch_bounds__(256)
void jbf_kernel(const float* __restrict__ tpl,
                const float* __restrict__ vec,
                float* __restrict__ out) {
    constexpr float KVAL  = -0.125f;  // -1/(2*sigma_spatial^2)
    constexpr float SIDIV = 50.0f;    // 1/(2*sigma_intensity^2)

    __shared__ __align__(16) float smem[NCH][HALO_H][HALO_W];

    const int tid = threadIdx.x;
    const int x0  = blockIdx.x * TS_X;
    const int y0  = blockIdx.y * TS_Y;

    // interior: whole 20x72 halo window in-bounds (no zero padding needed)
    const bool interior = (blockIdx.x >= 1) & (blockIdx.x <= 28) &
                          (blockIdx.y >= 1) & (blockIdx.y <= 66);

    if (interior) {
        // flat f4 index per channel: idx in [0,360); row=idx/18, col4=idx%18
        const int i0  = tid;
        const int i1  = tid + 256;
        const bool p1 = (i1 < F4_PER_CH);          // tid < 104
        const int i1c = p1 ? i1 : 0;
        const int r0 = i0 / F4_PER_ROW, c0 = i0 - r0 * F4_PER_ROW;
        const int r1 = i1c / F4_PER_ROW, c1 = i1c - r1 * F4_PER_ROW;
        const int off0 = r0 * IMG_W + c0 * 4;
        const int off1 = r1 * IMG_W + c1 * 4;
        const int tl   = (y0 - 2) * IMG_W + (x0 - 2);   // top-left of halo

        f4u v[2 * NCH];
#pragma unroll
        for (int ch = 0; ch < NCH; ++ch) {
            const float* __restrict__ src =
                (ch < 3) ? (tpl + ch * IMG_HW) : (vec + (ch - 3) * IMG_HW);
            v[2 * ch]     = *(const f4u*)(src + tl + off0);
            v[2 * ch + 1] = *(const f4u*)(src + tl + off1);
        }
#pragma unroll
        for (int ch = 0; ch < NCH; ++ch) {
            float4* d0 = (float4*)&smem[ch][r0][c0 * 4];
            d0->x = v[2 * ch].x; d0->y = v[2 * ch].y;
            d0->z = v[2 * ch].z; d0->w = v[2 * ch].w;
            if (p1) {
                float4* d1 = (float4*)&smem[ch][r1][c1 * 4];
                d1->x = v[2 * ch + 1].x; d1->y = v[2 * ch + 1].y;
                d1->z = v[2 * ch + 1].z; d1->w = v[2 * ch + 1].w;
            }
        }
    } else {
        // border: scalar bounds-checked staging with zero fill
#pragma unroll
        for (int c = 0; c < NCH; ++c) {
            const float* __restrict__ src =
                (c < 3) ? (tpl + c * IMG_HW) : (vec + (c - 3) * IMG_HW);
#pragma unroll
            for (int i = tid; i < HALO_H * HALO_W; i += 256) {
                const int r   = i / HALO_W;
                const int col = i - r * HALO_W;
                const int gy  = y0 + r - 2;
                const int gx  = x0 + col - 2;
                float val = 0.0f;
                if (gy >= 0 && gy < IMG_H && gx >= 0 && gx < IMG_W)
                    val = src[gy * IMG_W + gx];
                smem[c][r][col] = val;
            }
        }
    }
    __syncthreads();

    const int tx = tid & 15;   // 16 threads across
    const int ty = tid >> 4;   // 16 rows
    const int lx = tx * 4;     // first of 4 pixels this thread owns (halo col)

    float num0[4] = {0.f, 0.f, 0.f, 0.f};
    float num1[4] = {0.f, 0.f, 0.f, 0.f};
    float den [4] = {0.f, 0.f, 0.f, 0.f};

    float c0[4], c1[4], c2[4];
#pragma unroll
    for (int px = 0; px < 4; ++px) {
        c0[px] = smem[0][ty + 2][lx + 2 + px];
        c1[px] = smem[1][ty + 2][lx + 2 + px];
        c2[px] = smem[2][ty + 2][lx + 2 + px];
    }

#pragma unroll
    for (int dy = 0; dy < 5; ++dy) {
        const int row = ty + dy;
        float4 a0 = *(const float4*)&smem[0][row][lx];
        float4 b0 = *(const float4*)&smem[0][row][lx + 4];
        float4 a1 = *(const float4*)&smem[1][row][lx];
        float4 b1 = *(const float4*)&smem[1][row][lx + 4];
        float4 a2 = *(const float4*)&smem[2][row][lx];
        float4 b2 = *(const float4*)&smem[2][row][lx + 4];
        float4 av0 = *(const float4*)&smem[3][row][lx];
        float4 bv0 = *(const float4*)&smem[3][row][lx + 4];
        float4 av1 = *(const float4*)&smem[4][row][lx];
        float4 bv1 = *(const float4*)&smem[4][row][lx + 4];

        const float w0[8]  = {a0.x, a0.y, a0.z, a0.w, b0.x, b0.y, b0.z, b0.w};
        const float w1[8]  = {a1.x, a1.y, a1.z, a1.w, b1.x, b1.y, b1.z, b1.w};
        const float w2[8]  = {a2.x, a2.y, a2.z, a2.w, b2.x, b2.y, b2.z, b2.w};
        const float wv0[8] = {av0.x, av0.y, av0.z, av0.w, bv0.x, bv0.y, bv0.z, bv0.w};
        const float wv1[8] = {av1.x, av1.y, av1.z, av1.w, bv1.x, bv1.y, bv1.z, bv1.w};

#pragma unroll
        for (int dx = 0; dx < 5; ++dx) {
#pragma unroll
            for (int px = 0; px < 4; ++px) {
                const int k = dx + px;
                const float d0 = c0[px] - w0[k];
                const float d1 = c1[px] - w1[k];
                const float d2 = c2[px] - w2[k];
                const float id = d0 * d0 + d1 * d1 + d2 * d2;
                const float t  = fabsf(KVAL - id * SIDIV);
                float coeff = 1.0f - t;
                coeff = fminf(fmaxf(coeff, 0.0f), 1.0f);
                num0[px] += wv0[k] * coeff;
                num1[px] += wv1[k] * coeff;
                den [px] += coeff;
            }
        }
    }

    const int gy = y0 + ty;
    if (gy < IMG_H) {
        const int gx = x0 + lx;
        float4 o0, o1;
        float r0 = __builtin_amdgcn_rcpf(den[0]);
        float r1 = __builtin_amdgcn_rcpf(den[1]);
        float r2 = __builtin_amdgcn_rcpf(den[2]);
        float r3 = __builtin_amdgcn_rcpf(den[3]);
        o0.x = num0[0] * r0; o0.y = num0[1] * r1; o0.z = num0[2] * r2; o0.w = num0[3] * r3;
        o1.x = num1[0] * r0; o1.y = num1[1] * r1; o1.z = num1[2] * r2; o1.w = num1[3] * r3;
        *(float4*)(out + (size_t)0 * IMG_HW + gy * IMG_W + gx) = o0;
        *(float4*)(out + (size_t)1 * IMG_HW + gy * IMG_W + gx) = o1;
    }
}

extern "C" void kernel_launch(void* const* d_in, const int* in_sizes, int n_in,
                              void* d_out, int out_size, void* d_ws, size_t ws_size,
                              hipStream_t stream) {
    const float* tpl = (const float*)d_in[0];
    const float* vec = (const float*)d_in[1];
    float* out = (float*)d_out;

    dim3 grid(IMG_W / TS_X, (IMG_H + TS_Y - 1) / TS_Y);  // 30 x 68
    jbf_kernel<<<grid, 256, 0, stream>>>(tpl, vec, out);
}